// Round 12
// baseline (2680.045 us; speedup 1.0000x reference)
//
#include <hip/hip_runtime.h>
#include <hip/hip_bf16.h>
#include <hip/hip_fp16.h>

#define NN 100000
#define EE 1000000
#define GG 512
#define HH 64
#define LL 7
#define NH (NN*HH)
#define GH (GG*HH)
#define EPS_GEN 1e-7f
#define EPS_BN 1e-5f
#define SCAN_BLKS 98   // ceil(NN/1024)
#define SLOTS 64
#define CONV_BLOCKS (NN / 16)   // 6250 blocks x 1 wave x 16 nodes (exact)

typedef _Float16 half8  __attribute__((ext_vector_type(8)));
typedef _Float16 half4  __attribute__((ext_vector_type(4)));
typedef _Float16 half2v __attribute__((ext_vector_type(2)));
typedef float    float4v __attribute__((ext_vector_type(4)));

__device__ __constant__ int c_atom_off[9] = {0,119,124,136,148,158,164,170,172};

// h16[n][c] = fp16( vn0[c] + sum_f atom_table[x[n][f]+off_f][c] )
__global__ void k_atom_enc(const float* __restrict__ atom_table,
                           const float* __restrict__ vn0,
                           const int* __restrict__ x,
                           _Float16* __restrict__ h16) {
    int tid = blockIdx.x * blockDim.x + threadIdx.x;
    int n = tid >> 6, c = tid & 63;
    if (n >= NN) return;
    float acc = vn0[c];
    const int* xr = x + n * 9;
    #pragma unroll
    for (int f = 0; f < 9; ++f) acc += atom_table[(xr[f] + c_atom_off[f]) * HH + c];
    h16[tid] = (_Float16)acc;
}

// merged prep: W16f = fp16 conv weights pre-permuted into MFMA B-fragment order;
// ctab16 = fp16 combined bond table (c = a0 + 5*a1 + 30*a2)
__global__ void k_prep(const float* __restrict__ W, const float* __restrict__ bond,
                       _Float16* __restrict__ W16f, _Float16* __restrict__ ctab16) {
    int i = blockIdx.x * blockDim.x + threadIdx.x;
    if (i < LL * 4096) {
        int l = i / 4096, r = i % 4096;
        int j = r & 7, lane = (r >> 3) & 63, kh = (r >> 9) & 1, t = r >> 10;
        int q = (lane >> 4) & 3, c = lane & 15;
        W16f[i] = (_Float16)W[l * 4096 + (kh * 32 + q * 8 + j) * 64 + t * 16 + c];
    } else {
        int k = i - LL * 4096;
        if (k < 60 * 64) {
            int cmb = k >> 6, lane = k & 63;
            int a0 = cmb % 5, a1 = (cmb / 5) % 6, a2 = cmb / 30;
            ctab16[k] = (_Float16)(bond[a0 * 64 + lane] + bond[(5 + a1) * 64 + lane]
                                   + bond[(11 + a2) * 64 + lane]);
        }
    }
}

// ---------------- CSR build ----------------

__global__ void k_count(const int* __restrict__ edge_index, int* __restrict__ cur) {
    int e = blockIdx.x * blockDim.x + threadIdx.x;
    if (e >= EE) return;
    atomicAdd(&cur[edge_index[EE + e]], 1);
}

__global__ void k_scan1(const int* __restrict__ cnt, int* __restrict__ rp, int* __restrict__ part) {
    __shared__ int s[256];
    int t = threadIdx.x, blk = blockIdx.x;
    int base = blk * 1024 + t * 4;
    int v0 = 0, v1 = 0, v2 = 0, v3 = 0;
    if (base + 3 < NN) {
        int4 q = *(const int4*)(cnt + base);
        v0 = q.x; v1 = q.y; v2 = q.z; v3 = q.w;
    } else {
        if (base + 0 < NN) v0 = cnt[base + 0];
        if (base + 1 < NN) v1 = cnt[base + 1];
        if (base + 2 < NN) v2 = cnt[base + 2];
        if (base + 3 < NN) v3 = cnt[base + 3];
    }
    int s4 = v0 + v1 + v2 + v3;
    s[t] = s4;
    __syncthreads();
    for (int off = 1; off < 256; off <<= 1) {
        int x = (t >= off) ? s[t - off] : 0;
        __syncthreads();
        s[t] += x;
        __syncthreads();
    }
    int excl = s[t] - s4;
    if (t == 255) part[blk] = s[255];
    if (base + 0 < NN) rp[base + 0] = excl;
    if (base + 1 < NN) rp[base + 1] = excl + v0;
    if (base + 2 < NN) rp[base + 2] = excl + v0 + v1;
    if (base + 3 < NN) rp[base + 3] = excl + v0 + v1 + v2;
}

__global__ void k_scan2(int* __restrict__ part) {
    __shared__ int s[128];
    int t = threadIdx.x;
    int v = (t < SCAN_BLKS) ? part[t] : 0;
    s[t] = v;
    __syncthreads();
    for (int off = 1; off < 128; off <<= 1) {
        int x = (t >= off) ? s[t - off] : 0;
        __syncthreads();
        s[t] += x;
        __syncthreads();
    }
    if (t < SCAN_BLKS) part[t] = s[t] - v;
}

__global__ void k_scan3(int* __restrict__ rp, const int* __restrict__ part) {
    int i = blockIdx.x * blockDim.x + threadIdx.x;
    if (i < NN) rp[i] += part[i >> 10];
    if (i == 0) rp[NN] = EE;
}

// edge record: src(17b) | combo(6b)<<17
__global__ void k_fill(const int* __restrict__ edge_index, const int* __restrict__ edge_attr,
                       const int* __restrict__ rp, int* __restrict__ cur,
                       unsigned int* __restrict__ edges) {
    int e = blockIdx.x * blockDim.x + threadIdx.x;
    if (e >= EE) return;
    int src = edge_index[e];
    int dst = edge_index[EE + e];
    int combo = edge_attr[e * 3] + 5 * edge_attr[e * 3 + 1] + 30 * edge_attr[e * 3 + 2];
    unsigned int rec = (unsigned int)src | ((unsigned int)combo << 17);
    int slot = rp[dst] + atomicAdd(&cur[dst], 1);
    edges[slot] = rec;
}

// ---------------- conv: gather/aggregate -> MFMA GEMM (+res) + stats ----------------
// 1 wave per block (8 waves/EU), 16 nodes; 32-lane group per node.
// Non-temporal res loads / out stores; last block folds stats via ticket.
__global__ __launch_bounds__(64, 8) void k_conv_mfma(
        const _Float16* __restrict__ h16, const float* res,
        const int* __restrict__ rp, const unsigned int* __restrict__ edges,
        const _Float16* __restrict__ ctab16, const _Float16* __restrict__ W16f,
        const float* __restrict__ bvec,
        float* __restrict__ out, float* __restrict__ statsPart,
        int* __restrict__ ticket, float* __restrict__ ms) {
    __shared__ __align__(16) _Float16 sA[16 * 64];   // 16 rows x 128B
    int lane = threadIdx.x;
    int g  = lane >> 5;          // node group 0/1
    int sg = (lane >> 4) & 1;    // edge parity sub-group
    int cc = (lane & 15) * 4;    // channel base (half4)
    int q = lane >> 4;           // mfma quad
    int c = lane & 15;           // mfma col

    // B fragments: pre-permuted, 8 coalesced half8 loads
    const half8* wf = (const half8*)W16f;
    half8 bf[4][2];
    #pragma unroll
    for (int t = 0; t < 4; ++t) {
        bf[t][0] = wf[(t * 2 + 0) * 64 + lane];
        bf[t][1] = wf[(t * 2 + 1) * 64 + lane];
    }

    int n0 = blockIdx.x * 16;

    // ---- phase 1: aggregation, one node per 32-lane group ----
    #pragma unroll 1
    for (int i = 0; i < 8; ++i) {
        int n = n0 + g * 8 + i;
        float ax = 0.f, ay = 0.f, az = 0.f, aw = 0.f;
        int beg = rp[n], end = rp[n + 1];
        int deg = end - beg;
        int j = beg;
        for (; j + 8 <= end; j += 8) {     // 8 edges: sub-group sg takes j+sg,+2,+4,+6
            unsigned int r0 = edges[j + sg];
            unsigned int r1 = edges[j + 2 + sg];
            unsigned int r2 = edges[j + 4 + sg];
            unsigned int r3 = edges[j + 6 + sg];
            half4 h0 = *(const half4*)(h16 + (size_t)(r0 & 0x1FFFF) * 64 + cc);
            half4 t0 = *(const half4*)(ctab16 + ((r0 >> 17) & 63) * 64 + cc);
            half4 h1 = *(const half4*)(h16 + (size_t)(r1 & 0x1FFFF) * 64 + cc);
            half4 t1 = *(const half4*)(ctab16 + ((r1 >> 17) & 63) * 64 + cc);
            half4 h2 = *(const half4*)(h16 + (size_t)(r2 & 0x1FFFF) * 64 + cc);
            half4 t2 = *(const half4*)(ctab16 + ((r2 >> 17) & 63) * 64 + cc);
            half4 h3 = *(const half4*)(h16 + (size_t)(r3 & 0x1FFFF) * 64 + cc);
            half4 t3 = *(const half4*)(ctab16 + ((r3 >> 17) & 63) * 64 + cc);
            ax += fmaxf((float)h0[0] + (float)t0[0], 0.f) + fmaxf((float)h1[0] + (float)t1[0], 0.f)
                + fmaxf((float)h2[0] + (float)t2[0], 0.f) + fmaxf((float)h3[0] + (float)t3[0], 0.f);
            ay += fmaxf((float)h0[1] + (float)t0[1], 0.f) + fmaxf((float)h1[1] + (float)t1[1], 0.f)
                + fmaxf((float)h2[1] + (float)t2[1], 0.f) + fmaxf((float)h3[1] + (float)t3[1], 0.f);
            az += fmaxf((float)h0[2] + (float)t0[2], 0.f) + fmaxf((float)h1[2] + (float)t1[2], 0.f)
                + fmaxf((float)h2[2] + (float)t2[2], 0.f) + fmaxf((float)h3[2] + (float)t3[2], 0.f);
            aw += fmaxf((float)h0[3] + (float)t0[3], 0.f) + fmaxf((float)h1[3] + (float)t1[3], 0.f)
                + fmaxf((float)h2[3] + (float)t2[3], 0.f) + fmaxf((float)h3[3] + (float)t3[3], 0.f);
        }
        for (; j < end; j += 4) {          // masked tail: 2 edges per sub-group
            int i0 = j + sg, i1 = j + 2 + sg;
            bool v0 = i0 < end, v1 = i1 < end;
            unsigned int r0 = edges[v0 ? i0 : beg];
            unsigned int r1 = edges[v1 ? i1 : beg];
            half4 h0 = *(const half4*)(h16 + (size_t)(r0 & 0x1FFFF) * 64 + cc);
            half4 t0 = *(const half4*)(ctab16 + ((r0 >> 17) & 63) * 64 + cc);
            half4 h1 = *(const half4*)(h16 + (size_t)(r1 & 0x1FFFF) * 64 + cc);
            half4 t1 = *(const half4*)(ctab16 + ((r1 >> 17) & 63) * 64 + cc);
            if (v0) {
                ax += fmaxf((float)h0[0] + (float)t0[0], 0.f);
                ay += fmaxf((float)h0[1] + (float)t0[1], 0.f);
                az += fmaxf((float)h0[2] + (float)t0[2], 0.f);
                aw += fmaxf((float)h0[3] + (float)t0[3], 0.f);
            }
            if (v1) {
                ax += fmaxf((float)h1[0] + (float)t1[0], 0.f);
                ay += fmaxf((float)h1[1] + (float)t1[1], 0.f);
                az += fmaxf((float)h1[2] + (float)t1[2], 0.f);
                aw += fmaxf((float)h1[3] + (float)t1[3], 0.f);
            }
        }
        // reduce across sub-groups (lane bit 4); replicates
        ax += __shfl_xor(ax, 16, 64); ay += __shfl_xor(ay, 16, 64);
        az += __shfl_xor(az, 16, 64); aw += __shfl_xor(aw, 16, 64);
        half4 sv = *(const half4*)(h16 + (size_t)n * 64 + cc);
        float ed = (float)deg * EPS_GEN;
        ax += (float)sv[0] + ed; ay += (float)sv[1] + ed;
        az += (float)sv[2] + ed; aw += (float)sv[3] + ed;
        if (sg == 0) {
            half4 pk;
            pk[0] = (_Float16)ax; pk[1] = (_Float16)ay;
            pk[2] = (_Float16)az; pk[3] = (_Float16)aw;
            *(half4*)(&sA[(g * 8 + i) * 64 + cc]) = pk;
        }
    }
    __builtin_amdgcn_s_waitcnt(0);   // single-wave block: drain own ds_writes

    // ---- phase 2: MFMA ----
    half8 af0 = *(const half8*)(sA + c * 64 + q * 8);         // kh=0
    half8 af1 = *(const half8*)(sA + c * 64 + 32 + q * 8);    // kh=1
    float4v d[4];
    #pragma unroll
    for (int t = 0; t < 4; ++t) {
        d[t] = (float4v){0.f, 0.f, 0.f, 0.f};
        d[t] = __builtin_amdgcn_mfma_f32_16x16x32_f16(af0, bf[t][0], d[t], 0, 0, 0);
        d[t] = __builtin_amdgcn_mfma_f32_16x16x32_f16(af1, bf[t][1], d[t], 0, 0, 0);
    }

    // ---- epilogue: bias + residual + store (non-temporal) + stats partials ----
    float ps[4], pq[4];
    #pragma unroll
    for (int t = 0; t < 4; ++t) { ps[t] = 0.f; pq[t] = 0.f; }
    #pragma unroll
    for (int t = 0; t < 4; ++t) {
        float bz = bvec[t * 16 + c];
        #pragma unroll
        for (int r = 0; r < 4; ++r) {
            int row = n0 + q * 4 + r;
            float val = d[t][r] + bz;
            size_t off = (size_t)row * 64 + t * 16 + c;
            if (res) val += __builtin_nontemporal_load(&res[off]);
            __builtin_nontemporal_store(val, &out[off]);
            ps[t] += val;
            pq[t] = fmaf(val, val, pq[t]);
        }
    }
    #pragma unroll
    for (int t = 0; t < 4; ++t) {
        ps[t] += __shfl_xor(ps[t], 16, 64); ps[t] += __shfl_xor(ps[t], 32, 64);
        pq[t] += __shfl_xor(pq[t], 16, 64); pq[t] += __shfl_xor(pq[t], 32, 64);
    }
    float* sp = statsPart + (blockIdx.x & (SLOTS - 1)) * 128;
    if (lane < 16) {
        #pragma unroll
        for (int t = 0; t < 4; ++t) {
            atomicAdd(&sp[t * 16 + lane], ps[t]);
            atomicAdd(&sp[64 + t * 16 + lane], pq[t]);
        }
    }

    // ---- last block folds the 64 slot-partials into ms = {mu, rstd} ----
    __threadfence();                              // order sp atomics before ticket
    int tk = 0;
    if (lane == 0) tk = atomicAdd(ticket, 1);
    tk = __shfl(tk, 0, 64);
    if (tk == CONV_BLOCKS - 1) {
        __threadfence();
        float s = 0.f, qq = 0.f;
        for (int i = 0; i < SLOTS; ++i) {
            s  += __hip_atomic_load(&statsPart[i * 128 + lane], __ATOMIC_RELAXED,
                                    __HIP_MEMORY_SCOPE_AGENT);
            qq += __hip_atomic_load(&statsPart[i * 128 + 64 + lane], __ATOMIC_RELAXED,
                                    __HIP_MEMORY_SCOPE_AGENT);
        }
        float mu = s * (1.f / NN);
        float var = qq * (1.f / NN) - mu * mu;
        ms[lane] = mu;
        ms[64 + lane] = rsqrtf(var + EPS_BN);
    }
}

// ---------------- BN / pooling ----------------

// h16 = fp16(relu(bn(h))); vt[batch[n]] += run-length aggregated; chunk=8 nodes/wave
__global__ void k_bn_relu_vt2(const float* __restrict__ h, const float* __restrict__ ms,
                              const float* __restrict__ gamma, const float* __restrict__ beta,
                              const int* __restrict__ batch,
                              _Float16* __restrict__ h16, float* __restrict__ vt) {
    int lane = threadIdx.x & 63;
    int w = blockIdx.x * 4 + (threadIdx.x >> 6);
    int n0 = w * 8;
    if (n0 >= NN) return;
    int n1 = min(n0 + 8, NN);
    float mu = ms[lane];
    float inv = ms[64 + lane] * gamma[lane];
    float bet = beta[lane];
    float acc = 0.f;
    int gcur = batch[n0];
    for (int n = n0; n < n1; ++n) {
        float v = fmaxf((h[(size_t)n * 64 + lane] - mu) * inv + bet, 0.f);
        h16[(size_t)n * 64 + lane] = (_Float16)v;
        int g = batch[n];
        if (g != gcur) {
            atomicAdd(&vt[(size_t)gcur * 64 + lane], acc);
            acc = 0.f; gcur = g;
        }
        acc += v;
    }
    atomicAdd(&vt[(size_t)gcur * 64 + lane], acc);
}

// VN GEMM over 512 rows (32 blocks, 4 rows/wave): out = (bnrelu?(in) + add) @ W + b
__global__ void k_vn_gemm(float* __restrict__ in, int clear_in,
                          const float* in_stats, const float* in_g, const float* in_be,
                          const float* addmat, const float* add_stats,
                          const float* add_g, const float* add_be,
                          const float* addvec,
                          const float* __restrict__ W, const float* __restrict__ bvec,
                          float* __restrict__ out, float* __restrict__ out_stats) {
    __shared__ float sW[4096];
    __shared__ float sRed[2][4][64];
    for (int i = threadIdx.x; i < 4096; i += 256) sW[i] = W[i];
    __syncthreads();
    int lane = threadIdx.x & 63, wv = threadIdx.x >> 6;
    int w = blockIdx.x * 4 + wv;          // 128 waves, 4 rows each
    float imu = 0.f, iinv = 0.f, ibe = 0.f;
    if (in_stats) {
        float mu = in_stats[lane] * (1.f / GG);
        float var = in_stats[64 + lane] * (1.f / GG) - mu * mu;
        imu = mu; iinv = rsqrtf(var + EPS_BN) * in_g[lane]; ibe = in_be[lane];
    }
    float amu = 0.f, ainv = 0.f, abe = 0.f;
    if (addmat && add_stats) {
        float mu = add_stats[lane] * (1.f / GG);
        float var = add_stats[64 + lane] * (1.f / GG) - mu * mu;
        amu = mu; ainv = rsqrtf(var + EPS_BN) * add_g[lane]; abe = add_be[lane];
    }
    float av_const = addvec ? addvec[lane] : 0.f;
    float psum = 0.f, psq = 0.f;
    for (int r = w * 4; r < w * 4 + 4; ++r) {
        float va = in[r * 64 + lane];
        if (clear_in) in[r * 64 + lane] = 0.f;
        if (in_stats) va = fmaxf((va - imu) * iinv + ibe, 0.f);
        if (addmat) va += fmaxf((addmat[r * 64 + lane] - amu) * ainv + abe, 0.f);
        va += av_const;
        float acc = bvec[lane];
        #pragma unroll
        for (int k = 0; k < 64; ++k)
            acc = fmaf(__shfl(va, k, 64), sW[k * 64 + lane], acc);
        out[r * 64 + lane] = acc;
        psum += acc; psq = fmaf(acc, acc, psq);
    }
    sRed[0][wv][lane] = psum;
    sRed[1][wv][lane] = psq;
    __syncthreads();
    if (threadIdx.x < 64) {
        float s = 0.f, q = 0.f;
        #pragma unroll
        for (int i = 0; i < 4; ++i) { s += sRed[0][i][threadIdx.x]; q += sRed[1][i][threadIdx.x]; }
        atomicAdd(&out_stats[threadIdx.x], s);
        atomicAdd(&out_stats[64 + threadIdx.x], q);
    }
}

// h16[n] += bnrelu(t2)[batch[n]]  (BN affine computed inline from 128-float stats)
__global__ void k_addvn16(_Float16* __restrict__ h16, const float* __restrict__ t2,
                          const float* __restrict__ stats,
                          const float* __restrict__ g2, const float* __restrict__ be2,
                          const int* __restrict__ batch) {
    int tid = blockIdx.x * blockDim.x + threadIdx.x;
    int n = tid >> 5, p = tid & 31;
    if (n >= NN) return;
    int c0 = p * 2, c1 = p * 2 + 1;
    float mu0 = stats[c0] * (1.f / GG), mu1 = stats[c1] * (1.f / GG);
    float v0 = stats[64 + c0] * (1.f / GG) - mu0 * mu0;
    float v1 = stats[64 + c1] * (1.f / GG) - mu1 * mu1;
    float i0 = rsqrtf(v0 + EPS_BN) * g2[c0], i1 = rsqrtf(v1 + EPS_BN) * g2[c1];
    int g = batch[n];
    float2 t = *(const float2*)(t2 + (size_t)g * 64 + c0);
    float a0 = fmaxf((t.x - mu0) * i0 + be2[c0], 0.f);
    float a1 = fmaxf((t.y - mu1) * i1 + be2[c1], 0.f);
    half2v hv = *(half2v*)(h16 + (size_t)n * 64 + c0);
    half2v o;
    o[0] = (_Float16)((float)hv[0] + a0);
    o[1] = (_Float16)((float)hv[1] + a1);
    *(half2v*)(h16 + (size_t)n * 64 + c0) = o;
}

// final BN + mean-pool, run-length aggregated; chunk=32
__global__ void k_pool2(const float* __restrict__ h, const float* __restrict__ ms,
                        const float* __restrict__ gamma, const float* __restrict__ beta,
                        const int* __restrict__ batch,
                        float* __restrict__ out, float* __restrict__ cnt) {
    int lane = threadIdx.x & 63;
    int w = blockIdx.x * 4 + (threadIdx.x >> 6);
    int n0 = w * 32;
    if (n0 >= NN) return;
    int n1 = min(n0 + 32, NN);
    float mu = ms[lane];
    float inv = ms[64 + lane] * gamma[lane];
    float bet = beta[lane];
    float acc = 0.f;
    int run = 0;
    int gcur = batch[n0];
    for (int n = n0; n < n1; ++n) {
        float v = (h[(size_t)n * 64 + lane] - mu) * inv + bet;
        int g = batch[n];
        if (g != gcur) {
            atomicAdd(&out[(size_t)gcur * 64 + lane], acc);
            if (lane == 0) atomicAdd(&cnt[gcur], (float)run);
            acc = 0.f; run = 0; gcur = g;
        }
        acc += v; run++;
    }
    atomicAdd(&out[(size_t)gcur * 64 + lane], acc);
    if (lane == 0) atomicAdd(&cnt[gcur], (float)run);
}

__global__ void k_div(float* __restrict__ out, const float* __restrict__ cnt) {
    int tid = blockIdx.x * blockDim.x + threadIdx.x;
    if (tid >= GH) return;
    out[tid] /= fmaxf(cnt[tid >> 6], 1.0f);
}

extern "C" void kernel_launch(void* const* d_in, const int* in_sizes, int n_in,
                              void* d_out, int out_size, void* d_ws, size_t ws_size,
                              hipStream_t stream) {
    const float* atom_table = (const float*)d_in[0];
    const float* bond_table = (const float*)d_in[1];
    const float* vn0   = (const float*)d_in[2];
    const float* gcn_W = (const float*)d_in[3];
    const float* gcn_b = (const float*)d_in[4];
    const float* ng    = (const float*)d_in[5];
    const float* nb    = (const float*)d_in[6];
    const float* vn_W1 = (const float*)d_in[7];
    const float* vn_b1 = (const float*)d_in[8];
    const float* vn_g1 = (const float*)d_in[9];
    const float* vn_be1= (const float*)d_in[10];
    const float* vn_W2 = (const float*)d_in[11];
    const float* vn_b2 = (const float*)d_in[12];
    const float* vn_g2 = (const float*)d_in[13];
    const float* vn_be2= (const float*)d_in[14];
    const int* x          = (const int*)d_in[15];
    const int* edge_index = (const int*)d_in[16];
    const int* edge_attr  = (const int*)d_in[17];
    const int* batch      = (const int*)d_in[18];

    float* ws = (float*)d_ws;
    float* hB   = ws;                                 // NH fp32 (running h)
    _Float16* h16 = (_Float16*)(ws + (size_t)NH);     // NH fp16 (gather source)
    float* vt   = ws + (size_t)NH + NH / 2;           // GH
    float* t1   = vt + GH;                            // GH
    float* t2   = t1 + GH;                            // GH
    float* convStatsP = t2 + GH;                      // 7 * SLOTS * 128
    float* msAll      = convStatsP + 7 * SLOTS * 128; // 7 * 128
    float* vn1Stats   = msAll + 7 * 128;              // 6*128
    float* vn2Stats   = vn1Stats + 6 * 128;           // 6*128
    int*   tickets    = (int*)(vn2Stats + 6 * 128);   // 8 ints (zeroed with stats)
    float* cnt    = (float*)(tickets + 8);            // GG
    _Float16* ctab16 = (_Float16*)(cnt + GG);         // 60*64 fp16
    _Float16* W16f   = ctab16 + 60 * 64;              // 7*4096 fp16 (fragment order)
    int*   rp     = (int*)(W16f + LL * 4096);         // NN+1
    int*   cur    = rp + (NN + 1);                    // NN
    int*   part   = cur + NN;                         // 128
    unsigned int* edges = (unsigned int*)(part + 128);  // EE

    const int blkN = NH / 256;               // 25000
    const int blkG = (GH + 255) / 256;       // 128
    const int blkE = (EE + 255) / 256;       // 3907
    const int blkRL = ((NN + 7) / 8 + 3) / 4;   // 3125
    const int blkPL = ((NN + 31) / 32 + 3) / 4;
    const int blkAV = (NN * 32) / 256;       // 12500
    const int blkPR = (LL * 4096 + 60 * 64 + 255) / 256;  // 127
    float* outp = (float*)d_out;

    k_atom_enc<<<blkN, 256, 0, stream>>>(atom_table, vn0, x, h16);
    k_prep<<<blkPR, 256, 0, stream>>>(gcn_W, bond_table, W16f, ctab16);
    // zero stats partials + ms + vn stats + tickets in one memset
    hipMemsetAsync(convStatsP, 0, ((7 * SLOTS * 128 + 7 * 128 + 12 * 128) + 8) * 4, stream);
    hipMemsetAsync(vt, 0, (size_t)GH * 4, stream);

    // ---- CSR build ----
    hipMemsetAsync(cur, 0, (size_t)NN * 4, stream);
    k_count<<<blkE, 256, 0, stream>>>(edge_index, cur);
    k_scan1<<<SCAN_BLKS, 256, 0, stream>>>(cur, rp, part);
    k_scan2<<<1, 128, 0, stream>>>(part);
    k_scan3<<<(NN + 255) / 256, 256, 0, stream>>>(rp, part);
    hipMemsetAsync(cur, 0, (size_t)NN * 4, stream);
    k_fill<<<blkE, 256, 0, stream>>>(edge_index, edge_attr, rp, cur, edges);

    // ---- layer 0: hB = (h16 + agg(h16)) @ W0 + b0 ----
    k_conv_mfma<<<CONV_BLOCKS, 64, 0, stream>>>(h16, nullptr, rp, edges, ctab16, W16f,
                                                gcn_b, hB, convStatsP, tickets, msAll);

    for (int l = 1; l < LL; ++l) {
        k_bn_relu_vt2<<<blkRL, 256, 0, stream>>>(hB, msAll + (size_t)(l - 1) * 128,
                                                 ng + (size_t)(l - 1) * HH,
                                                 nb + (size_t)(l - 1) * HH, batch, h16, vt);
        // t1 = (vt + vn_prev) @ W1 + b1 ; vn_prev = l==1 ? vn0 : bnrelu(t2, vn2Stats[l-2])
        if (l == 1)
            k_vn_gemm<<<32, 256, 0, stream>>>(vt, 1, nullptr, nullptr, nullptr,
                                              nullptr, nullptr, nullptr, nullptr, vn0,
                                              vn_W1, vn_b1, t1, vn1Stats);
        else
            k_vn_gemm<<<32, 256, 0, stream>>>(vt, 1, nullptr, nullptr, nullptr,
                                              t2, vn2Stats + (size_t)(l - 2) * 128,
                                              vn_g2 + (size_t)(l - 2) * HH,
                                              vn_be2 + (size_t)(l - 2) * HH, nullptr,
                                              vn_W1 + (size_t)(l - 1) * 4096,
                                              vn_b1 + (size_t)(l - 1) * HH, t1,
                                              vn1Stats + (size_t)(l - 1) * 128);
        // t2 = bnrelu(t1) @ W2 + b2
        k_vn_gemm<<<32, 256, 0, stream>>>(t1, 0, vn1Stats + (size_t)(l - 1) * 128,
                                          vn_g1 + (size_t)(l - 1) * HH,
                                          vn_be1 + (size_t)(l - 1) * HH,
                                          nullptr, nullptr, nullptr, nullptr, nullptr,
                                          vn_W2 + (size_t)(l - 1) * 4096,
                                          vn_b2 + (size_t)(l - 1) * HH, t2,
                                          vn2Stats + (size_t)(l - 1) * 128);
        // h16 += bnrelu(t2)[batch]
        k_addvn16<<<blkAV, 256, 0, stream>>>(h16, t2, vn2Stats + (size_t)(l - 1) * 128,
                                             vn_g2 + (size_t)(l - 1) * HH,
                                             vn_be2 + (size_t)(l - 1) * HH, batch);

        k_conv_mfma<<<CONV_BLOCKS, 64, 0, stream>>>(h16, hB, rp, edges, ctab16,
                                                    W16f + (size_t)l * 4096,
                                                    gcn_b + (size_t)l * HH, hB,
                                                    convStatsP + (size_t)l * SLOTS * 128,
                                                    tickets + l, msAll + (size_t)l * 128);
    }

    // ---- final BN + mean pool (ms from last conv's fold) ----
    hipMemsetAsync(outp, 0, (size_t)GH * 4, stream);
    hipMemsetAsync(cnt, 0, (size_t)GG * 4, stream);
    k_pool2<<<blkPL, 256, 0, stream>>>(hB, msAll + (size_t)6 * 128,
                                       ng + (size_t)6 * HH, nb + (size_t)6 * HH,
                                       batch, outp, cnt);
    k_div<<<blkG, 256, 0, stream>>>(outp, cnt);
}

// Round 13
// 999.261 us; speedup vs baseline: 2.6820x; 2.6820x over previous
//
#include <hip/hip_runtime.h>
#include <hip/hip_bf16.h>
#include <hip/hip_fp16.h>

#define NN 100000
#define EE 1000000
#define GG 512
#define HH 64
#define LL 7
#define NH (NN*HH)
#define GH (GG*HH)
#define EPS_GEN 1e-7f
#define EPS_BN 1e-5f
#define SCAN_BLKS 98   // ceil(NN/1024)
#define SLOTS 64
#define CONV_BLOCKS (NN / 16)   // 6250 blocks x 1 wave x 16 nodes (exact)

typedef _Float16 half8  __attribute__((ext_vector_type(8)));
typedef _Float16 half4  __attribute__((ext_vector_type(4)));
typedef _Float16 half2v __attribute__((ext_vector_type(2)));
typedef float    float4v __attribute__((ext_vector_type(4)));

__device__ __constant__ int c_atom_off[9] = {0,119,124,136,148,158,164,170,172};

// h16[n][c] = fp16( vn0[c] + sum_f atom_table[x[n][f]+off_f][c] )
__global__ void k_atom_enc(const float* __restrict__ atom_table,
                           const float* __restrict__ vn0,
                           const int* __restrict__ x,
                           _Float16* __restrict__ h16) {
    int tid = blockIdx.x * blockDim.x + threadIdx.x;
    int n = tid >> 6, c = tid & 63;
    if (n >= NN) return;
    float acc = vn0[c];
    const int* xr = x + n * 9;
    #pragma unroll
    for (int f = 0; f < 9; ++f) acc += atom_table[(xr[f] + c_atom_off[f]) * HH + c];
    h16[tid] = (_Float16)acc;
}

// merged prep: W16f = fp16 conv weights pre-permuted into MFMA B-fragment order;
// ctab16 = fp16 combined bond table (c = a0 + 5*a1 + 30*a2)
__global__ void k_prep(const float* __restrict__ W, const float* __restrict__ bond,
                       _Float16* __restrict__ W16f, _Float16* __restrict__ ctab16) {
    int i = blockIdx.x * blockDim.x + threadIdx.x;
    if (i < LL * 4096) {
        int l = i / 4096, r = i % 4096;
        int j = r & 7, lane = (r >> 3) & 63, kh = (r >> 9) & 1, t = r >> 10;
        int q = (lane >> 4) & 3, c = lane & 15;
        W16f[i] = (_Float16)W[l * 4096 + (kh * 32 + q * 8 + j) * 64 + t * 16 + c];
    } else {
        int k = i - LL * 4096;
        if (k < 60 * 64) {
            int cmb = k >> 6, lane = k & 63;
            int a0 = cmb % 5, a1 = (cmb / 5) % 6, a2 = cmb / 30;
            ctab16[k] = (_Float16)(bond[a0 * 64 + lane] + bond[(5 + a1) * 64 + lane]
                                   + bond[(11 + a2) * 64 + lane]);
        }
    }
}

// ---------------- CSR build ----------------

__global__ void k_count(const int* __restrict__ edge_index, int* __restrict__ cur) {
    int e = blockIdx.x * blockDim.x + threadIdx.x;
    if (e >= EE) return;
    atomicAdd(&cur[edge_index[EE + e]], 1);
}

__global__ void k_scan1(const int* __restrict__ cnt, int* __restrict__ rp, int* __restrict__ part) {
    __shared__ int s[256];
    int t = threadIdx.x, blk = blockIdx.x;
    int base = blk * 1024 + t * 4;
    int v0 = 0, v1 = 0, v2 = 0, v3 = 0;
    if (base + 3 < NN) {
        int4 q = *(const int4*)(cnt + base);
        v0 = q.x; v1 = q.y; v2 = q.z; v3 = q.w;
    } else {
        if (base + 0 < NN) v0 = cnt[base + 0];
        if (base + 1 < NN) v1 = cnt[base + 1];
        if (base + 2 < NN) v2 = cnt[base + 2];
        if (base + 3 < NN) v3 = cnt[base + 3];
    }
    int s4 = v0 + v1 + v2 + v3;
    s[t] = s4;
    __syncthreads();
    for (int off = 1; off < 256; off <<= 1) {
        int x = (t >= off) ? s[t - off] : 0;
        __syncthreads();
        s[t] += x;
        __syncthreads();
    }
    int excl = s[t] - s4;
    if (t == 255) part[blk] = s[255];
    if (base + 0 < NN) rp[base + 0] = excl;
    if (base + 1 < NN) rp[base + 1] = excl + v0;
    if (base + 2 < NN) rp[base + 2] = excl + v0 + v1;
    if (base + 3 < NN) rp[base + 3] = excl + v0 + v1 + v2;
}

__global__ void k_scan2(int* __restrict__ part) {
    __shared__ int s[128];
    int t = threadIdx.x;
    int v = (t < SCAN_BLKS) ? part[t] : 0;
    s[t] = v;
    __syncthreads();
    for (int off = 1; off < 128; off <<= 1) {
        int x = (t >= off) ? s[t - off] : 0;
        __syncthreads();
        s[t] += x;
        __syncthreads();
    }
    if (t < SCAN_BLKS) part[t] = s[t] - v;
}

__global__ void k_scan3(int* __restrict__ rp, const int* __restrict__ part) {
    int i = blockIdx.x * blockDim.x + threadIdx.x;
    if (i < NN) rp[i] += part[i >> 10];
    if (i == 0) rp[NN] = EE;
}

// edge record: src(17b) | combo(6b)<<17
__global__ void k_fill(const int* __restrict__ edge_index, const int* __restrict__ edge_attr,
                       const int* __restrict__ rp, int* __restrict__ cur,
                       unsigned int* __restrict__ edges) {
    int e = blockIdx.x * blockDim.x + threadIdx.x;
    if (e >= EE) return;
    int src = edge_index[e];
    int dst = edge_index[EE + e];
    int combo = edge_attr[e * 3] + 5 * edge_attr[e * 3 + 1] + 30 * edge_attr[e * 3 + 2];
    unsigned int rec = (unsigned int)src | ((unsigned int)combo << 17);
    int slot = rp[dst] + atomicAdd(&cur[dst], 1);
    edges[slot] = rec;
}

// ---------------- conv: gather/aggregate -> MFMA GEMM (+res) + stats ----------------
// 1 wave per block (8 waves/EU -> 32 waves/CU), 16 nodes; 32-lane group per node.
// NOTE (R12 lesson): no non-temporal hints here — out/res (hB) are L2-hot and re-read
// by the next kernels; no device-scope fences per block (L2 writeback storm).
__global__ __launch_bounds__(64, 8) void k_conv_mfma(
        const _Float16* __restrict__ h16, const float* res,
        const int* __restrict__ rp, const unsigned int* __restrict__ edges,
        const _Float16* __restrict__ ctab16, const _Float16* __restrict__ W16f,
        const float* __restrict__ bvec,
        float* __restrict__ out, float* __restrict__ statsPart) {
    __shared__ __align__(16) _Float16 sA[16 * 64];   // 16 rows x 128B
    int lane = threadIdx.x;
    int g  = lane >> 5;          // node group 0/1
    int sg = (lane >> 4) & 1;    // edge parity sub-group
    int cc = (lane & 15) * 4;    // channel base (half4)
    int q = lane >> 4;           // mfma quad
    int c = lane & 15;           // mfma col

    // B fragments: pre-permuted, 8 coalesced half8 loads
    const half8* wf = (const half8*)W16f;
    half8 bf[4][2];
    #pragma unroll
    for (int t = 0; t < 4; ++t) {
        bf[t][0] = wf[(t * 2 + 0) * 64 + lane];
        bf[t][1] = wf[(t * 2 + 1) * 64 + lane];
    }

    int n0 = blockIdx.x * 16;

    // ---- phase 1: aggregation, one node per 32-lane group ----
    #pragma unroll 1
    for (int i = 0; i < 8; ++i) {
        int n = n0 + g * 8 + i;
        float ax = 0.f, ay = 0.f, az = 0.f, aw = 0.f;
        int beg = rp[n], end = rp[n + 1];
        int deg = end - beg;
        int j = beg;
        for (; j + 8 <= end; j += 8) {     // 8 edges: sub-group sg takes j+sg,+2,+4,+6
            unsigned int r0 = edges[j + sg];
            unsigned int r1 = edges[j + 2 + sg];
            unsigned int r2 = edges[j + 4 + sg];
            unsigned int r3 = edges[j + 6 + sg];
            half4 h0 = *(const half4*)(h16 + (size_t)(r0 & 0x1FFFF) * 64 + cc);
            half4 t0 = *(const half4*)(ctab16 + ((r0 >> 17) & 63) * 64 + cc);
            half4 h1 = *(const half4*)(h16 + (size_t)(r1 & 0x1FFFF) * 64 + cc);
            half4 t1 = *(const half4*)(ctab16 + ((r1 >> 17) & 63) * 64 + cc);
            half4 h2 = *(const half4*)(h16 + (size_t)(r2 & 0x1FFFF) * 64 + cc);
            half4 t2 = *(const half4*)(ctab16 + ((r2 >> 17) & 63) * 64 + cc);
            half4 h3 = *(const half4*)(h16 + (size_t)(r3 & 0x1FFFF) * 64 + cc);
            half4 t3 = *(const half4*)(ctab16 + ((r3 >> 17) & 63) * 64 + cc);
            ax += fmaxf((float)h0[0] + (float)t0[0], 0.f) + fmaxf((float)h1[0] + (float)t1[0], 0.f)
                + fmaxf((float)h2[0] + (float)t2[0], 0.f) + fmaxf((float)h3[0] + (float)t3[0], 0.f);
            ay += fmaxf((float)h0[1] + (float)t0[1], 0.f) + fmaxf((float)h1[1] + (float)t1[1], 0.f)
                + fmaxf((float)h2[1] + (float)t2[1], 0.f) + fmaxf((float)h3[1] + (float)t3[1], 0.f);
            az += fmaxf((float)h0[2] + (float)t0[2], 0.f) + fmaxf((float)h1[2] + (float)t1[2], 0.f)
                + fmaxf((float)h2[2] + (float)t2[2], 0.f) + fmaxf((float)h3[2] + (float)t3[2], 0.f);
            aw += fmaxf((float)h0[3] + (float)t0[3], 0.f) + fmaxf((float)h1[3] + (float)t1[3], 0.f)
                + fmaxf((float)h2[3] + (float)t2[3], 0.f) + fmaxf((float)h3[3] + (float)t3[3], 0.f);
        }
        for (; j < end; j += 4) {          // masked tail: 2 edges per sub-group
            int i0 = j + sg, i1 = j + 2 + sg;
            bool v0 = i0 < end, v1 = i1 < end;
            unsigned int r0 = edges[v0 ? i0 : beg];
            unsigned int r1 = edges[v1 ? i1 : beg];
            half4 h0 = *(const half4*)(h16 + (size_t)(r0 & 0x1FFFF) * 64 + cc);
            half4 t0 = *(const half4*)(ctab16 + ((r0 >> 17) & 63) * 64 + cc);
            half4 h1 = *(const half4*)(h16 + (size_t)(r1 & 0x1FFFF) * 64 + cc);
            half4 t1 = *(const half4*)(ctab16 + ((r1 >> 17) & 63) * 64 + cc);
            if (v0) {
                ax += fmaxf((float)h0[0] + (float)t0[0], 0.f);
                ay += fmaxf((float)h0[1] + (float)t0[1], 0.f);
                az += fmaxf((float)h0[2] + (float)t0[2], 0.f);
                aw += fmaxf((float)h0[3] + (float)t0[3], 0.f);
            }
            if (v1) {
                ax += fmaxf((float)h1[0] + (float)t1[0], 0.f);
                ay += fmaxf((float)h1[1] + (float)t1[1], 0.f);
                az += fmaxf((float)h1[2] + (float)t1[2], 0.f);
                aw += fmaxf((float)h1[3] + (float)t1[3], 0.f);
            }
        }
        // reduce across sub-groups (lane bit 4); replicates
        ax += __shfl_xor(ax, 16, 64); ay += __shfl_xor(ay, 16, 64);
        az += __shfl_xor(az, 16, 64); aw += __shfl_xor(aw, 16, 64);
        half4 sv = *(const half4*)(h16 + (size_t)n * 64 + cc);
        float ed = (float)deg * EPS_GEN;
        ax += (float)sv[0] + ed; ay += (float)sv[1] + ed;
        az += (float)sv[2] + ed; aw += (float)sv[3] + ed;
        if (sg == 0) {
            half4 pk;
            pk[0] = (_Float16)ax; pk[1] = (_Float16)ay;
            pk[2] = (_Float16)az; pk[3] = (_Float16)aw;
            *(half4*)(&sA[(g * 8 + i) * 64 + cc]) = pk;
        }
    }
    __builtin_amdgcn_s_waitcnt(0);   // single-wave block: drain own ds_writes

    // ---- phase 2: MFMA ----
    half8 af0 = *(const half8*)(sA + c * 64 + q * 8);         // kh=0
    half8 af1 = *(const half8*)(sA + c * 64 + 32 + q * 8);    // kh=1
    float4v d[4];
    #pragma unroll
    for (int t = 0; t < 4; ++t) {
        d[t] = (float4v){0.f, 0.f, 0.f, 0.f};
        d[t] = __builtin_amdgcn_mfma_f32_16x16x32_f16(af0, bf[t][0], d[t], 0, 0, 0);
        d[t] = __builtin_amdgcn_mfma_f32_16x16x32_f16(af1, bf[t][1], d[t], 0, 0, 0);
    }

    // ---- epilogue: bias + residual + store + stats partials ----
    float ps[4], pq[4];
    #pragma unroll
    for (int t = 0; t < 4; ++t) { ps[t] = 0.f; pq[t] = 0.f; }
    #pragma unroll
    for (int t = 0; t < 4; ++t) {
        float bz = bvec[t * 16 + c];
        #pragma unroll
        for (int r = 0; r < 4; ++r) {
            int row = n0 + q * 4 + r;
            float val = d[t][r] + bz;
            size_t off = (size_t)row * 64 + t * 16 + c;
            if (res) val += res[off];
            out[off] = val;
            ps[t] += val;
            pq[t] = fmaf(val, val, pq[t]);
        }
    }
    #pragma unroll
    for (int t = 0; t < 4; ++t) {
        ps[t] += __shfl_xor(ps[t], 16, 64); ps[t] += __shfl_xor(ps[t], 32, 64);
        pq[t] += __shfl_xor(pq[t], 16, 64); pq[t] += __shfl_xor(pq[t], 32, 64);
    }
    float* sp = statsPart + (blockIdx.x & (SLOTS - 1)) * 128;
    if (lane < 16) {
        #pragma unroll
        for (int t = 0; t < 4; ++t) {
            atomicAdd(&sp[t * 16 + lane], ps[t]);
            atomicAdd(&sp[64 + t * 16 + lane], pq[t]);
        }
    }
}

// fold 64 slot-partials -> ms[0..63]=mu, ms[64..127]=rstd
__global__ void k_finstats(const float* __restrict__ sp, float rows_inv, float* __restrict__ ms) {
    int lane = threadIdx.x;
    float s = 0.f, q = 0.f;
    for (int i = 0; i < SLOTS; ++i) { s += sp[i * 128 + lane]; q += sp[i * 128 + 64 + lane]; }
    float mu = s * rows_inv;
    float var = q * rows_inv - mu * mu;
    ms[lane] = mu;
    ms[64 + lane] = rsqrtf(var + EPS_BN);
}

// ---------------- BN / pooling ----------------

// h16 = fp16(relu(bn(h))); vt[batch[n]] += run-length aggregated; chunk=8 nodes/wave
__global__ void k_bn_relu_vt2(const float* __restrict__ h, const float* __restrict__ ms,
                              const float* __restrict__ gamma, const float* __restrict__ beta,
                              const int* __restrict__ batch,
                              _Float16* __restrict__ h16, float* __restrict__ vt) {
    int lane = threadIdx.x & 63;
    int w = blockIdx.x * 4 + (threadIdx.x >> 6);
    int n0 = w * 8;
    if (n0 >= NN) return;
    int n1 = min(n0 + 8, NN);
    float mu = ms[lane];
    float inv = ms[64 + lane] * gamma[lane];
    float bet = beta[lane];
    float acc = 0.f;
    int gcur = batch[n0];
    for (int n = n0; n < n1; ++n) {
        float v = fmaxf((h[(size_t)n * 64 + lane] - mu) * inv + bet, 0.f);
        h16[(size_t)n * 64 + lane] = (_Float16)v;
        int g = batch[n];
        if (g != gcur) {
            atomicAdd(&vt[(size_t)gcur * 64 + lane], acc);
            acc = 0.f; gcur = g;
        }
        acc += v;
    }
    atomicAdd(&vt[(size_t)gcur * 64 + lane], acc);
}

// VN GEMM over 512 rows (32 blocks, 4 rows/wave): out = (bnrelu?(in) + add) @ W + b
__global__ void k_vn_gemm(float* __restrict__ in, int clear_in,
                          const float* in_stats, const float* in_g, const float* in_be,
                          const float* addmat, const float* add_stats,
                          const float* add_g, const float* add_be,
                          const float* addvec,
                          const float* __restrict__ W, const float* __restrict__ bvec,
                          float* __restrict__ out, float* __restrict__ out_stats) {
    __shared__ float sW[4096];
    __shared__ float sRed[2][4][64];
    for (int i = threadIdx.x; i < 4096; i += 256) sW[i] = W[i];
    __syncthreads();
    int lane = threadIdx.x & 63, wv = threadIdx.x >> 6;
    int w = blockIdx.x * 4 + wv;          // 128 waves, 4 rows each
    float imu = 0.f, iinv = 0.f, ibe = 0.f;
    if (in_stats) {
        float mu = in_stats[lane] * (1.f / GG);
        float var = in_stats[64 + lane] * (1.f / GG) - mu * mu;
        imu = mu; iinv = rsqrtf(var + EPS_BN) * in_g[lane]; ibe = in_be[lane];
    }
    float amu = 0.f, ainv = 0.f, abe = 0.f;
    if (addmat && add_stats) {
        float mu = add_stats[lane] * (1.f / GG);
        float var = add_stats[64 + lane] * (1.f / GG) - mu * mu;
        amu = mu; ainv = rsqrtf(var + EPS_BN) * add_g[lane]; abe = add_be[lane];
    }
    float av_const = addvec ? addvec[lane] : 0.f;
    float psum = 0.f, psq = 0.f;
    for (int r = w * 4; r < w * 4 + 4; ++r) {
        float va = in[r * 64 + lane];
        if (clear_in) in[r * 64 + lane] = 0.f;
        if (in_stats) va = fmaxf((va - imu) * iinv + ibe, 0.f);
        if (addmat) va += fmaxf((addmat[r * 64 + lane] - amu) * ainv + abe, 0.f);
        va += av_const;
        float acc = bvec[lane];
        #pragma unroll
        for (int k = 0; k < 64; ++k)
            acc = fmaf(__shfl(va, k, 64), sW[k * 64 + lane], acc);
        out[r * 64 + lane] = acc;
        psum += acc; psq = fmaf(acc, acc, psq);
    }
    sRed[0][wv][lane] = psum;
    sRed[1][wv][lane] = psq;
    __syncthreads();
    if (threadIdx.x < 64) {
        float s = 0.f, q = 0.f;
        #pragma unroll
        for (int i = 0; i < 4; ++i) { s += sRed[0][i][threadIdx.x]; q += sRed[1][i][threadIdx.x]; }
        atomicAdd(&out_stats[threadIdx.x], s);
        atomicAdd(&out_stats[64 + threadIdx.x], q);
    }
}

// h16[n] += bnrelu(t2)[batch[n]]  (BN affine computed inline from 128-float stats)
__global__ void k_addvn16(_Float16* __restrict__ h16, const float* __restrict__ t2,
                          const float* __restrict__ stats,
                          const float* __restrict__ g2, const float* __restrict__ be2,
                          const int* __restrict__ batch) {
    int tid = blockIdx.x * blockDim.x + threadIdx.x;
    int n = tid >> 5, p = tid & 31;
    if (n >= NN) return;
    int c0 = p * 2, c1 = p * 2 + 1;
    float mu0 = stats[c0] * (1.f / GG), mu1 = stats[c1] * (1.f / GG);
    float v0 = stats[64 + c0] * (1.f / GG) - mu0 * mu0;
    float v1 = stats[64 + c1] * (1.f / GG) - mu1 * mu1;
    float i0 = rsqrtf(v0 + EPS_BN) * g2[c0], i1 = rsqrtf(v1 + EPS_BN) * g2[c1];
    int g = batch[n];
    float2 t = *(const float2*)(t2 + (size_t)g * 64 + c0);
    float a0 = fmaxf((t.x - mu0) * i0 + be2[c0], 0.f);
    float a1 = fmaxf((t.y - mu1) * i1 + be2[c1], 0.f);
    half2v hv = *(half2v*)(h16 + (size_t)n * 64 + c0);
    half2v o;
    o[0] = (_Float16)((float)hv[0] + a0);
    o[1] = (_Float16)((float)hv[1] + a1);
    *(half2v*)(h16 + (size_t)n * 64 + c0) = o;
}

// final BN + mean-pool, run-length aggregated; chunk=16
__global__ void k_pool2(const float* __restrict__ h, const float* __restrict__ ms,
                        const float* __restrict__ gamma, const float* __restrict__ beta,
                        const int* __restrict__ batch,
                        float* __restrict__ out, float* __restrict__ cnt) {
    int lane = threadIdx.x & 63;
    int w = blockIdx.x * 4 + (threadIdx.x >> 6);
    int n0 = w * 16;
    if (n0 >= NN) return;
    int n1 = min(n0 + 16, NN);
    float mu = ms[lane];
    float inv = ms[64 + lane] * gamma[lane];
    float bet = beta[lane];
    float acc = 0.f;
    int run = 0;
    int gcur = batch[n0];
    for (int n = n0; n < n1; ++n) {
        float v = (h[(size_t)n * 64 + lane] - mu) * inv + bet;
        int g = batch[n];
        if (g != gcur) {
            atomicAdd(&out[(size_t)gcur * 64 + lane], acc);
            if (lane == 0) atomicAdd(&cnt[gcur], (float)run);
            acc = 0.f; run = 0; gcur = g;
        }
        acc += v; run++;
    }
    atomicAdd(&out[(size_t)gcur * 64 + lane], acc);
    if (lane == 0) atomicAdd(&cnt[gcur], (float)run);
}

__global__ void k_div(float* __restrict__ out, const float* __restrict__ cnt) {
    int tid = blockIdx.x * blockDim.x + threadIdx.x;
    if (tid >= GH) return;
    out[tid] /= fmaxf(cnt[tid >> 6], 1.0f);
}

extern "C" void kernel_launch(void* const* d_in, const int* in_sizes, int n_in,
                              void* d_out, int out_size, void* d_ws, size_t ws_size,
                              hipStream_t stream) {
    const float* atom_table = (const float*)d_in[0];
    const float* bond_table = (const float*)d_in[1];
    const float* vn0   = (const float*)d_in[2];
    const float* gcn_W = (const float*)d_in[3];
    const float* gcn_b = (const float*)d_in[4];
    const float* ng    = (const float*)d_in[5];
    const float* nb    = (const float*)d_in[6];
    const float* vn_W1 = (const float*)d_in[7];
    const float* vn_b1 = (const float*)d_in[8];
    const float* vn_g1 = (const float*)d_in[9];
    const float* vn_be1= (const float*)d_in[10];
    const float* vn_W2 = (const float*)d_in[11];
    const float* vn_b2 = (const float*)d_in[12];
    const float* vn_g2 = (const float*)d_in[13];
    const float* vn_be2= (const float*)d_in[14];
    const int* x          = (const int*)d_in[15];
    const int* edge_index = (const int*)d_in[16];
    const int* edge_attr  = (const int*)d_in[17];
    const int* batch      = (const int*)d_in[18];

    float* ws = (float*)d_ws;
    float* hB   = ws;                                 // NH fp32 (running h)
    _Float16* h16 = (_Float16*)(ws + (size_t)NH);     // NH fp16 (gather source)
    float* vt   = ws + (size_t)NH + NH / 2;           // GH
    float* t1   = vt + GH;                            // GH
    float* t2   = t1 + GH;                            // GH
    float* convStatsP = t2 + GH;                      // 7 * SLOTS * 128
    float* msAll      = convStatsP + 7 * SLOTS * 128; // 7 * 128
    float* vn1Stats   = msAll + 7 * 128;              // 6*128
    float* vn2Stats   = vn1Stats + 6 * 128;           // 6*128
    float* cnt    = vn2Stats + 6 * 128;               // GG
    _Float16* ctab16 = (_Float16*)(cnt + GG);         // 60*64 fp16
    _Float16* W16f   = ctab16 + 60 * 64;              // 7*4096 fp16 (fragment order)
    int*   rp     = (int*)(W16f + LL * 4096);         // NN+1
    int*   cur    = rp + (NN + 1);                    // NN
    int*   part   = cur + NN;                         // 128
    unsigned int* edges = (unsigned int*)(part + 128);  // EE

    const int blkN = NH / 256;               // 25000
    const int blkG = (GH + 255) / 256;       // 128
    const int blkE = (EE + 255) / 256;       // 3907
    const int blkRL = ((NN + 7) / 8 + 3) / 4;   // 3125
    const int blkPL = ((NN + 15) / 16 + 3) / 4; // 1563
    const int blkAV = (NN * 32) / 256;       // 12500
    const int blkPR = (LL * 4096 + 60 * 64 + 255) / 256;  // 127
    float* outp = (float*)d_out;

    k_atom_enc<<<blkN, 256, 0, stream>>>(atom_table, vn0, x, h16);
    k_prep<<<blkPR, 256, 0, stream>>>(gcn_W, bond_table, W16f, ctab16);
    hipMemsetAsync(convStatsP, 0, (7 * SLOTS * 128 + 7 * 128 + 12 * 128) * 4, stream);
    hipMemsetAsync(vt, 0, (size_t)GH * 4, stream);

    // ---- CSR build ----
    hipMemsetAsync(cur, 0, (size_t)NN * 4, stream);
    k_count<<<blkE, 256, 0, stream>>>(edge_index, cur);
    k_scan1<<<SCAN_BLKS, 256, 0, stream>>>(cur, rp, part);
    k_scan2<<<1, 128, 0, stream>>>(part);
    k_scan3<<<(NN + 255) / 256, 256, 0, stream>>>(rp, part);
    hipMemsetAsync(cur, 0, (size_t)NN * 4, stream);
    k_fill<<<blkE, 256, 0, stream>>>(edge_index, edge_attr, rp, cur, edges);

    // ---- layer 0: hB = (h16 + agg(h16)) @ W0 + b0 ----
    k_conv_mfma<<<CONV_BLOCKS, 64, 0, stream>>>(h16, nullptr, rp, edges, ctab16, W16f,
                                                gcn_b, hB, convStatsP);

    for (int l = 1; l < LL; ++l) {
        k_finstats<<<1, 64, 0, stream>>>(convStatsP + (size_t)(l - 1) * SLOTS * 128,
                                         1.f / NN, msAll + (size_t)(l - 1) * 128);
        k_bn_relu_vt2<<<blkRL, 256, 0, stream>>>(hB, msAll + (size_t)(l - 1) * 128,
                                                 ng + (size_t)(l - 1) * HH,
                                                 nb + (size_t)(l - 1) * HH, batch, h16, vt);
        // t1 = (vt + vn_prev) @ W1 + b1 ; vn_prev = l==1 ? vn0 : bnrelu(t2, vn2Stats[l-2])
        if (l == 1)
            k_vn_gemm<<<32, 256, 0, stream>>>(vt, 1, nullptr, nullptr, nullptr,
                                              nullptr, nullptr, nullptr, nullptr, vn0,
                                              vn_W1, vn_b1, t1, vn1Stats);
        else
            k_vn_gemm<<<32, 256, 0, stream>>>(vt, 1, nullptr, nullptr, nullptr,
                                              t2, vn2Stats + (size_t)(l - 2) * 128,
                                              vn_g2 + (size_t)(l - 2) * HH,
                                              vn_be2 + (size_t)(l - 2) * HH, nullptr,
                                              vn_W1 + (size_t)(l - 1) * 4096,
                                              vn_b1 + (size_t)(l - 1) * HH, t1,
                                              vn1Stats + (size_t)(l - 1) * 128);
        // t2 = bnrelu(t1) @ W2 + b2
        k_vn_gemm<<<32, 256, 0, stream>>>(t1, 0, vn1Stats + (size_t)(l - 1) * 128,
                                          vn_g1 + (size_t)(l - 1) * HH,
                                          vn_be1 + (size_t)(l - 1) * HH,
                                          nullptr, nullptr, nullptr, nullptr, nullptr,
                                          vn_W2 + (size_t)(l - 1) * 4096,
                                          vn_b2 + (size_t)(l - 1) * HH, t2,
                                          vn2Stats + (size_t)(l - 1) * 128);
        // h16 += bnrelu(t2)[batch]
        k_addvn16<<<blkAV, 256, 0, stream>>>(h16, t2, vn2Stats + (size_t)(l - 1) * 128,
                                             vn_g2 + (size_t)(l - 1) * HH,
                                             vn_be2 + (size_t)(l - 1) * HH, batch);

        k_conv_mfma<<<CONV_BLOCKS, 64, 0, stream>>>(h16, hB, rp, edges, ctab16,
                                                    W16f + (size_t)l * 4096,
                                                    gcn_b + (size_t)l * HH, hB,
                                                    convStatsP + (size_t)l * SLOTS * 128);
    }

    // ---- final BN + mean pool ----
    k_finstats<<<1, 64, 0, stream>>>(convStatsP + (size_t)6 * SLOTS * 128,
                                     1.f / NN, msAll + (size_t)6 * 128);
    hipMemsetAsync(outp, 0, (size_t)GH * 4, stream);
    hipMemsetAsync(cnt, 0, (size_t)GG * 4, stream);
    k_pool2<<<blkPL, 256, 0, stream>>>(hB, msAll + (size_t)6 * 128,
                                       ng + (size_t)6 * HH, nb + (size_t)6 * HH,
                                       batch, outp, cnt);
    k_div<<<blkG, 256, 0, stream>>>(outp, cnt);
}